// Round 15
// baseline (88.757 us; speedup 1.0000x reference)
//
#include <hip/hip_runtime.h>
#include <math.h>

#define N 128
#define HID 512
#define NH (N * HID)                 // 65536
#define SNH ((size_t)N * NH)         // 8388608 elements per s
#define NPAIRS (N * (N + 1) / 2)     // 8256
#define REP 4                        // instrumentation: idempotent repeats

// workspace layout (float offsets) — same as R11/R13
#define OFF_PSC 0                    // PScol [2][8][128][512]
#define OFF_PSR 4194304              // PSrow [2][4][128][512]
#define OFF_DG  4718592              // Dg    [2][128][512]
#define OFF_XR  4849664              // Xr    [2][128][512]
#define OFF_YC  4980736              // Yc    [2][128][512]
#define OFF_SV  5111808              // Sv    [2][512]
#define OFF_DB  5112832              // Db    [2][512]

typedef float vf4 __attribute__((ext_vector_type(4)));
union F4 { vf4 v; float f[4]; };

// ---------------------------------------------------------------------------
// K1: R13/R11 dense-cube p1, REP-wrapped.
// ---------------------------------------------------------------------------
__global__ __launch_bounds__(512)
void schur_p1(const float* __restrict__ x, float* __restrict__ PScol,
              float* __restrict__ PSrow, float* __restrict__ Dg) {
    const int u  = blockIdx.x;            // 0..255
    const int hq = u & 3;
    const int bq = (u >> 2) & 3;
    const int g  = (u >> 4) & 7;
    const int s  = u >> 7;                // 0..1
    const int tid = threadIdx.x;
    const int f   = tid & 31;             // float4 within h-quarter
    const int bg  = tid >> 5;             // 0..15, 2 b's each
    const int b0  = bq * 32 + bg * 2;
    const int hoff = hq * 128 + f * 4;

    const float* xs   = x + (size_t)s * SNH;
    const float* base = xs + (size_t)(g * 16) * NH + b0 * HID + hoff;

    __shared__ F4 rowred[8][16][32];      // 64 KiB

    for (int rep = 0; rep < REP; ++rep) {
        F4 acc0, acc1;
        acc0.v = (vf4)(0.f); acc1.v = (vf4)(0.f);

        #pragma unroll
        for (int c = 0; c < 2; ++c) {
            #pragma unroll
            for (int al = 0; al < 8; ++al) {
                const float* p = base + (size_t)(c * 8 + al) * NH;
                F4 v0; v0.v = *reinterpret_cast<const vf4*>(p);
                F4 v1; v1.v = *reinterpret_cast<const vf4*>(p + HID);
                acc0.v += v0.v;
                acc1.v += v1.v;
                F4 rs; rs.v = v0.v + v1.v;
                rowred[al][bg][f] = rs;
            }
            __syncthreads();
            if (tid < 256) {
                const int ar = tid >> 5;      // 0..7
                const int f2 = tid & 31;
                F4 t; t.v = (vf4)(0.f);
                #pragma unroll
                for (int k = 0; k < 16; ++k) t.v += rowred[ar][k][f2].v;
                const int a = g * 16 + c * 8 + ar;
                *reinterpret_cast<vf4*>(PSrow +
                    ((((size_t)s * 4 + bq) * N + a) * HID + hq * 128 + f2 * 4)) = t.v;
            }
            __syncthreads();
        }

        *reinterpret_cast<vf4*>(PScol +
            ((((size_t)s * 8 + g) * N + b0) * HID + hoff)) = acc0.v;
        *reinterpret_cast<vf4*>(PScol +
            ((((size_t)s * 8 + g) * N + b0 + 1) * HID + hoff)) = acc1.v;

        if (bq == (g >> 1)) {
            const int ar = tid >> 5;          // 0..15
            const int f2 = tid & 31;
            const int a  = g * 16 + ar;
            const vf4 dv = *reinterpret_cast<const vf4*>(
                xs + (size_t)a * NH + a * HID + hq * 128 + f2 * 4);
            *reinterpret_cast<vf4*>(Dg +
                (((size_t)s * N + a) * HID + hq * 128 + f2 * 4)) = dv;
        }
        __syncthreads();
    }
}

// ---------------------------------------------------------------------------
// K2: R13 vectorized stats, REP-wrapped.
// ---------------------------------------------------------------------------
__global__ __launch_bounds__(256)
void schur_p2(const float* __restrict__ PScol, const float* __restrict__ PSrow,
              const float* __restrict__ Dg,
              float* __restrict__ Xr, float* __restrict__ Yc,
              float* __restrict__ Sv, float* __restrict__ Db) {
    const int bi = blockIdx.x;            // 0..31
    const int s  = bi >> 4;
    const int hc = bi & 15;               // 8 float4 per chunk
    const int tid = threadIdx.x;          // 0..255
    const int iq = tid >> 3;              // 0..31
    const int hf = tid & 7;
    const int h  = (hc * 8 + hf) * 4;     // float offset in [0,512)

    __shared__ F4 redT[32][8];
    __shared__ F4 redD[32][8];
    __shared__ F4 shS[8];

    for (int rep = 0; rep < REP; ++rep) {
        F4 sa[4], sb[4], dg[4];
        F4 T, D; T.v = (vf4)(0.f); D.v = (vf4)(0.f);
        #pragma unroll
        for (int k = 0; k < 4; ++k) {
            const int i = iq + 32 * k;
            F4 acc; acc.v = (vf4)(0.f);
            #pragma unroll
            for (int gg = 0; gg < 8; ++gg)
                acc.v += reinterpret_cast<const F4*>(
                    PScol + (((size_t)s * 8 + gg) * N + i) * HID + h)->v;
            sa[k] = acc; T.v += acc.v;
            F4 accb; accb.v = (vf4)(0.f);
            #pragma unroll
            for (int qq = 0; qq < 4; ++qq)
                accb.v += reinterpret_cast<const F4*>(
                    PSrow + (((size_t)s * 4 + qq) * N + i) * HID + h)->v;
            sb[k] = accb;
            dg[k].v = reinterpret_cast<const F4*>(
                Dg + ((size_t)s * N + i) * HID + h)->v;
            D.v += dg[k].v;
        }

        __syncthreads();                  // guard LDS reuse across reps
        redT[iq][hf] = T;
        redD[iq][hf] = D;
        __syncthreads();
        if (iq == 0) {
            F4 Tt, Dd; Tt.v = (vf4)(0.f); Dd.v = (vf4)(0.f);
            #pragma unroll
            for (int q = 0; q < 32; ++q) { Tt.v += redT[q][hf].v; Dd.v += redD[q][hf].v; }
            F4 sh, db_;
            sh.v  = (Tt.v - Dd.v) * (1.0f / 16256.0f);
            db_.v = Dd.v * (1.0f / 128.0f);
            *reinterpret_cast<vf4*>(Sv + s * HID + h) = sh.v;
            *reinterpret_cast<vf4*>(Db + s * HID + h) = db_.v;
            shS[hf] = sh;
        }
        __syncthreads();

        const F4 sh = shS[hf];
        const float inv = 1.0f / 16128.0f;
        const size_t base = (size_t)s * N * HID;
        #pragma unroll
        for (int k = 0; k < 4; ++k) {
            const int i = iq + 32 * k;
            F4 r, c, xr, yc;
            r.v = sa[k].v - dg[k].v - 127.0f * sh.v;
            c.v = sb[k].v - dg[k].v - 127.0f * sh.v;
            xr.v = (127.0f * r.v + c.v) * inv;
            yc.v = (127.0f * c.v + r.v) * inv;
            *reinterpret_cast<vf4*>(Xr + base + (size_t)i * HID + h) = xr.v;
            *reinterpret_cast<vf4*>(Yc + base + (size_t)i * HID + h) = yc.v;
        }
    }
}

// ---------------------------------------------------------------------------
// K3: R13 p3 (XCD swizzle, NT stores), REP-wrapped.
// ---------------------------------------------------------------------------
__global__ __launch_bounds__(256)
void schur_p3(const float* __restrict__ x, const float* __restrict__ w,
              const float* __restrict__ iso,
              const float* __restrict__ Xr, const float* __restrict__ Yc,
              const float* __restrict__ Sv, const float* __restrict__ Db,
              float* __restrict__ out) {
    const int t  = threadIdx.x;
    const int k  = t >> 7;                // pair slot 0/1
    const int ht = t & 127;
    const int hoff = ht * 4;

    float c[7];
    #pragma unroll
    for (int j = 0; j < 7; ++j) {
        float acc = 0.f;
        #pragma unroll
        for (int i = 0; i < 7; ++i) acc += w[i * 7 + j] * iso[i * 7 + j];
        c[j] = acc;
    }
    const float c1 = c[0], c2 = c[1], c3 = c[2], c4 = c[3], c5 = c[4];
    const float al = 0.5f * (c[5] + c[6]);
    const float be = 0.5f * (c[5] - c[6]);

    const int bid = blockIdx.x;
    const int swz = (bid & 7) * 258 + (bid >> 3);   // 2064 = 8*258, bijective
    const int pg0 = swz * 8;

    #define TRI_OFF(aa) ((aa) * N - (((aa) * ((aa) - 1)) >> 1))
    for (int rep = 0; rep < REP; ++rep) {
        #pragma unroll
        for (int it = 0; it < 4; ++it) {
            const int pg = pg0 + it * 2 + k;      // global pair id, < 16512
            const int s  = (pg >= NPAIRS) ? 1 : 0;
            const int p  = pg - s * NPAIRS;

            int a = (int)((257.0f - sqrtf((float)(66049 - 8 * p))) * 0.5f);
            if (a < 0) a = 0;
            if (a > N - 1) a = N - 1;
            while (a > 0 && TRI_OFF(a) > p) --a;
            while (TRI_OFF(a + 1) <= p) ++a;
            const int b = a + (p - TRI_OFF(a));

            const size_t sbase    = (size_t)s * SNH;
            const size_t statbase = (size_t)s * N * HID;

            if (a == b) {
                F4 v;  v.v  = *reinterpret_cast<const vf4*>(x + sbase + ((size_t)a * N + a) * HID + hoff);
                F4 db; db.v = *reinterpret_cast<const vf4*>(Db + (size_t)s * HID + hoff);
                F4 o;
                #pragma unroll
                for (int j = 0; j < 4; ++j)
                    o.f[j] = c1 * db.f[j] + c2 * (v.f[j] - db.f[j]);
                __builtin_nontemporal_store(o.v,
                    reinterpret_cast<vf4*>(out + sbase + ((size_t)a * N + a) * HID + hoff));
                continue;
            }

            F4 va;  va.v  = *reinterpret_cast<const vf4*>(x + sbase + ((size_t)a * N + b) * HID + hoff);
            F4 vb;  vb.v  = *reinterpret_cast<const vf4*>(x + sbase + ((size_t)b * N + a) * HID + hoff);
            F4 xra; xra.v = *reinterpret_cast<const vf4*>(Xr + statbase + (size_t)a * HID + hoff);
            F4 xrb; xrb.v = *reinterpret_cast<const vf4*>(Xr + statbase + (size_t)b * HID + hoff);
            F4 yca; yca.v = *reinterpret_cast<const vf4*>(Yc + statbase + (size_t)a * HID + hoff);
            F4 ycb; ycb.v = *reinterpret_cast<const vf4*>(Yc + statbase + (size_t)b * HID + hoff);
            F4 sh;  sh.v  = *reinterpret_cast<const vf4*>(Sv + (size_t)s * HID + hoff);

            F4 oab, oba;
            #pragma unroll
            for (int j = 0; j < 4; ++j) {
                const float U = va.f[j] - sh.f[j] - xrb.f[j] - yca.f[j];
                const float V = vb.f[j] - sh.f[j] - xra.f[j] - ycb.f[j];
                oab.f[j] = c3 * sh.f[j] + c4 * xrb.f[j] + c5 * yca.f[j] + al * U + be * V;
                oba.f[j] = c3 * sh.f[j] + c4 * xra.f[j] + c5 * ycb.f[j] + al * V + be * U;
            }
            __builtin_nontemporal_store(oab.v,
                reinterpret_cast<vf4*>(out + sbase + ((size_t)a * N + b) * HID + hoff));
            __builtin_nontemporal_store(oba.v,
                reinterpret_cast<vf4*>(out + sbase + ((size_t)b * N + a) * HID + hoff));
        }
    }
}

extern "C" void kernel_launch(void* const* d_in, const int* in_sizes, int n_in,
                              void* d_out, int out_size, void* d_ws, size_t ws_size,
                              hipStream_t stream) {
    const float* x   = (const float*)d_in[0];
    const float* w   = (const float*)d_in[1];
    const float* iso = (const float*)d_in[2];
    float* out = (float*)d_out;
    float* ws  = (float*)d_ws;

    float* PScol = ws + OFF_PSC;
    float* PSrow = ws + OFF_PSR;
    float* Dg    = ws + OFF_DG;
    float* Xr    = ws + OFF_XR;
    float* Yc    = ws + OFF_YC;
    float* Sv    = ws + OFF_SV;
    float* Db    = ws + OFF_DB;

    schur_p1<<<256, 512, 0, stream>>>(x, PScol, PSrow, Dg);
    schur_p2<<<32, 256, 0, stream>>>(PScol, PSrow, Dg, Xr, Yc, Sv, Db);
    schur_p3<<<2064, 256, 0, stream>>>(x, w, iso, Xr, Yc, Sv, Db, out);
}

// Round 16
// 48.079 us; speedup vs baseline: 1.8461x; 1.8461x over previous
//
#include <hip/hip_runtime.h>
#include <math.h>

#define N 128
#define HID 512
#define NH (N * HID)                 // 65536
#define SNH ((size_t)N * NH)         // 8388608 elements per s
#define NPAIRS (N * (N + 1) / 2)     // 8256

// workspace layout (float offsets) — R11/R13 shape
#define OFF_PSC 0                    // PScol [2][8][128][512]
#define OFF_PSR 4194304              // PSrow [2][4][128][512]
#define OFF_DG  4718592              // Dg    [2][128][512]
#define OFF_AB  4849664              // A     [2][128][512]
#define OFF_BB  4980736              // B     [2][128][512]
#define OFF_S0  5111808              // S0    [2][512]
#define OFF_D0  5112832              // D0    [2][512]

typedef float vf4 __attribute__((ext_vector_type(4)));
union F4 { vf4 v; float f[4]; };

// ---------------------------------------------------------------------------
// K1: stride-free dense-cube partial sums (R11/R13 p1, VERBATIM — proven).
// ---------------------------------------------------------------------------
__global__ __launch_bounds__(512)
void schur_p1(const float* __restrict__ x, float* __restrict__ PScol,
              float* __restrict__ PSrow, float* __restrict__ Dg) {
    const int u  = blockIdx.x;            // 0..255
    const int hq = u & 3;
    const int bq = (u >> 2) & 3;
    const int g  = (u >> 4) & 7;
    const int s  = u >> 7;                // 0..1
    const int tid = threadIdx.x;
    const int f   = tid & 31;             // float4 within h-quarter
    const int bg  = tid >> 5;             // 0..15, 2 b's each
    const int b0  = bq * 32 + bg * 2;
    const int hoff = hq * 128 + f * 4;

    const float* xs   = x + (size_t)s * SNH;
    const float* base = xs + (size_t)(g * 16) * NH + b0 * HID + hoff;

    __shared__ F4 rowred[8][16][32];      // 64 KiB

    F4 acc0, acc1;
    acc0.v = (vf4)(0.f); acc1.v = (vf4)(0.f);

    #pragma unroll
    for (int c = 0; c < 2; ++c) {
        #pragma unroll
        for (int al = 0; al < 8; ++al) {
            const float* p = base + (size_t)(c * 8 + al) * NH;
            F4 v0; v0.v = *reinterpret_cast<const vf4*>(p);
            F4 v1; v1.v = *reinterpret_cast<const vf4*>(p + HID);
            acc0.v += v0.v;
            acc1.v += v1.v;
            F4 rs; rs.v = v0.v + v1.v;
            rowred[al][bg][f] = rs;
        }
        __syncthreads();
        if (tid < 256) {
            const int ar = tid >> 5;      // 0..7
            const int f2 = tid & 31;
            F4 t; t.v = (vf4)(0.f);
            #pragma unroll
            for (int k = 0; k < 16; ++k) t.v += rowred[ar][k][f2].v;
            const int a = g * 16 + c * 8 + ar;
            *reinterpret_cast<vf4*>(PSrow +
                ((((size_t)s * 4 + bq) * N + a) * HID + hq * 128 + f2 * 4)) = t.v;
        }
        __syncthreads();
    }

    *reinterpret_cast<vf4*>(PScol +
        ((((size_t)s * 8 + g) * N + b0) * HID + hoff)) = acc0.v;
    *reinterpret_cast<vf4*>(PScol +
        ((((size_t)s * 8 + g) * N + b0 + 1) * HID + hoff)) = acc1.v;

    if (bq == (g >> 1)) {
        const int ar = tid >> 5;          // 0..15
        const int f2 = tid & 31;
        const int a  = g * 16 + ar;
        const vf4 dv = *reinterpret_cast<const vf4*>(
            xs + (size_t)a * NH + a * HID + hq * 128 + f2 * 4);
        *reinterpret_cast<vf4*>(Dg +
            (((size_t)s * N + a) * HID + hq * 128 + f2 * 4)) = dv;
    }
}

// ---------------------------------------------------------------------------
// K2: fold partials -> stats -> PRE-COMBINED epilogue vectors:
//   A[i] = (c4-al)*xr[i] - be*yc[i]
//   B[i] = (c5-al)*yc[i] - be*xr[i]
//   S0   = (c3-al-be)*s ;  D0 = (c1-c2)*dbar
// so K3's per-element math collapses to 2 fma + 2 add per output.
// 32 blocks x 256 threads, all vf4 (R13 structure).
// ---------------------------------------------------------------------------
__global__ __launch_bounds__(256)
void schur_p2(const float* __restrict__ PScol, const float* __restrict__ PSrow,
              const float* __restrict__ Dg,
              const float* __restrict__ w, const float* __restrict__ iso,
              float* __restrict__ Ab, float* __restrict__ Bb,
              float* __restrict__ S0, float* __restrict__ D0) {
    const int bi = blockIdx.x;            // 0..31
    const int s  = bi >> 4;
    const int hc = bi & 15;               // 8 float4 per chunk
    const int tid = threadIdx.x;          // 0..255
    const int iq = tid >> 3;              // 0..31
    const int hf = tid & 7;
    const int h  = (hc * 8 + hf) * 4;     // float offset in [0,512)

    float c[7];
    #pragma unroll
    for (int j = 0; j < 7; ++j) {
        float acc = 0.f;
        #pragma unroll
        for (int i = 0; i < 7; ++i) acc += w[i * 7 + j] * iso[i * 7 + j];
        c[j] = acc;
    }
    const float al  = 0.5f * (c[5] + c[6]);
    const float be  = 0.5f * (c[5] - c[6]);
    const float kA  = c[3] - al;          // coeff of xr in A
    const float kB  = c[4] - al;          // coeff of yc in B
    const float kS  = c[2] - al - be;     // coeff of s in S0
    const float kD  = c[0] - c[1];        // coeff of dbar in D0

    F4 sa[4], sb[4], dg[4];
    F4 T, D; T.v = (vf4)(0.f); D.v = (vf4)(0.f);
    #pragma unroll
    for (int k = 0; k < 4; ++k) {
        const int i = iq + 32 * k;
        F4 acc; acc.v = (vf4)(0.f);
        #pragma unroll
        for (int gg = 0; gg < 8; ++gg)
            acc.v += reinterpret_cast<const F4*>(
                PScol + (((size_t)s * 8 + gg) * N + i) * HID + h)->v;
        sa[k] = acc; T.v += acc.v;
        F4 accb; accb.v = (vf4)(0.f);
        #pragma unroll
        for (int qq = 0; qq < 4; ++qq)
            accb.v += reinterpret_cast<const F4*>(
                PSrow + (((size_t)s * 4 + qq) * N + i) * HID + h)->v;
        sb[k] = accb;
        dg[k].v = reinterpret_cast<const F4*>(
            Dg + ((size_t)s * N + i) * HID + h)->v;
        D.v += dg[k].v;
    }

    __shared__ F4 redT[32][8];
    __shared__ F4 redD[32][8];
    __shared__ F4 shS[8];
    redT[iq][hf] = T;
    redD[iq][hf] = D;
    __syncthreads();
    if (iq == 0) {
        F4 Tt, Dd; Tt.v = (vf4)(0.f); Dd.v = (vf4)(0.f);
        #pragma unroll
        for (int q = 0; q < 32; ++q) { Tt.v += redT[q][hf].v; Dd.v += redD[q][hf].v; }
        F4 sh, s0, d0;
        sh.v = (Tt.v - Dd.v) * (1.0f / 16256.0f);   // /(n(n-1))
        s0.v = kS * sh.v;
        d0.v = kD * (Dd.v * (1.0f / 128.0f));
        *reinterpret_cast<vf4*>(S0 + s * HID + h) = s0.v;
        *reinterpret_cast<vf4*>(D0 + s * HID + h) = d0.v;
        shS[hf] = sh;
    }
    __syncthreads();

    const F4 sh = shS[hf];
    const float inv = 1.0f / 16128.0f;    // 1/(n(n-2))
    const size_t base = (size_t)s * N * HID;
    #pragma unroll
    for (int k = 0; k < 4; ++k) {
        const int i = iq + 32 * k;
        F4 r, cc, xr, yc, Av, Bv;
        r.v  = sa[k].v - dg[k].v - 127.0f * sh.v;
        cc.v = sb[k].v - dg[k].v - 127.0f * sh.v;
        xr.v = (127.0f * r.v + cc.v) * inv;
        yc.v = (127.0f * cc.v + r.v) * inv;
        Av.v = kA * xr.v - be * yc.v;
        Bv.v = kB * yc.v - be * xr.v;
        *reinterpret_cast<vf4*>(Ab + base + (size_t)i * HID + h) = Av.v;
        *reinterpret_cast<vf4*>(Bb + base + (size_t)i * HID + h) = Bv.v;
    }
}

// ---------------------------------------------------------------------------
// K3: output over triangular pairs, MINIMAL VALU epilogue:
//   oab = al*va + be*vb + (S0 + A[b] + B[a])
//   oba = al*vb + be*va + (S0 + A[a] + B[b])
//   diag: o = c2*v + D0
// 2064 blocks x 256 threads, XCD swizzle, NT stores (R13 skeleton).
// ---------------------------------------------------------------------------
__global__ __launch_bounds__(256)
void schur_p3(const float* __restrict__ x, const float* __restrict__ w,
              const float* __restrict__ iso,
              const float* __restrict__ Ab, const float* __restrict__ Bb,
              const float* __restrict__ S0, const float* __restrict__ D0,
              float* __restrict__ out) {
    const int t  = threadIdx.x;
    const int k  = t >> 7;                // pair slot 0/1
    const int ht = t & 127;
    const int hoff = ht * 4;

    float c[7];
    #pragma unroll
    for (int j = 0; j < 7; ++j) {
        float acc = 0.f;
        #pragma unroll
        for (int i = 0; i < 7; ++i) acc += w[i * 7 + j] * iso[i * 7 + j];
        c[j] = acc;
    }
    const float c2 = c[1];
    const float al = 0.5f * (c[5] + c[6]);
    const float be = 0.5f * (c[5] - c[6]);

    const int bid = blockIdx.x;
    const int swz = (bid & 7) * 258 + (bid >> 3);   // 2064 = 8*258, bijective
    const int pg0 = swz * 8;

    #define TRI_OFF(aa) ((aa) * N - (((aa) * ((aa) - 1)) >> 1))
    #pragma unroll
    for (int it = 0; it < 4; ++it) {
        const int pg = pg0 + it * 2 + k;      // global pair id, < 16512
        const int s  = (pg >= NPAIRS) ? 1 : 0;
        const int p  = pg - s * NPAIRS;

        int a = (int)((257.0f - sqrtf((float)(66049 - 8 * p))) * 0.5f);
        if (a < 0) a = 0;
        if (a > N - 1) a = N - 1;
        while (a > 0 && TRI_OFF(a) > p) --a;
        while (TRI_OFF(a + 1) <= p) ++a;
        const int b = a + (p - TRI_OFF(a));

        const size_t sbase    = (size_t)s * SNH;
        const size_t statbase = (size_t)s * N * HID;

        if (a == b) {
            F4 v;  v.v  = *reinterpret_cast<const vf4*>(x + sbase + ((size_t)a * N + a) * HID + hoff);
            F4 d0; d0.v = *reinterpret_cast<const vf4*>(D0 + (size_t)s * HID + hoff);
            F4 o;
            #pragma unroll
            for (int j = 0; j < 4; ++j)
                o.f[j] = fmaf(c2, v.f[j], d0.f[j]);
            __builtin_nontemporal_store(o.v,
                reinterpret_cast<vf4*>(out + sbase + ((size_t)a * N + a) * HID + hoff));
            continue;
        }

        F4 va;  va.v = *reinterpret_cast<const vf4*>(x + sbase + ((size_t)a * N + b) * HID + hoff);
        F4 vb;  vb.v = *reinterpret_cast<const vf4*>(x + sbase + ((size_t)b * N + a) * HID + hoff);
        F4 Aa;  Aa.v = *reinterpret_cast<const vf4*>(Ab + statbase + (size_t)a * HID + hoff);
        F4 Ab_; Ab_.v = *reinterpret_cast<const vf4*>(Ab + statbase + (size_t)b * HID + hoff);
        F4 Ba;  Ba.v = *reinterpret_cast<const vf4*>(Bb + statbase + (size_t)a * HID + hoff);
        F4 Bb_; Bb_.v = *reinterpret_cast<const vf4*>(Bb + statbase + (size_t)b * HID + hoff);
        F4 s0;  s0.v = *reinterpret_cast<const vf4*>(S0 + (size_t)s * HID + hoff);

        F4 oab, oba;
        #pragma unroll
        for (int j = 0; j < 4; ++j) {
            const float tab = s0.f[j] + Ab_.f[j] + Ba.f[j];
            const float tba = s0.f[j] + Aa.f[j] + Bb_.f[j];
            oab.f[j] = fmaf(al, va.f[j], fmaf(be, vb.f[j], tab));
            oba.f[j] = fmaf(al, vb.f[j], fmaf(be, va.f[j], tba));
        }
        __builtin_nontemporal_store(oab.v,
            reinterpret_cast<vf4*>(out + sbase + ((size_t)a * N + b) * HID + hoff));
        __builtin_nontemporal_store(oba.v,
            reinterpret_cast<vf4*>(out + sbase + ((size_t)b * N + a) * HID + hoff));
    }
}

extern "C" void kernel_launch(void* const* d_in, const int* in_sizes, int n_in,
                              void* d_out, int out_size, void* d_ws, size_t ws_size,
                              hipStream_t stream) {
    const float* x   = (const float*)d_in[0];
    const float* w   = (const float*)d_in[1];
    const float* iso = (const float*)d_in[2];
    float* out = (float*)d_out;
    float* ws  = (float*)d_ws;

    float* PScol = ws + OFF_PSC;
    float* PSrow = ws + OFF_PSR;
    float* Dg    = ws + OFF_DG;
    float* Ab    = ws + OFF_AB;
    float* Bb    = ws + OFF_BB;
    float* S0    = ws + OFF_S0;
    float* D0    = ws + OFF_D0;

    schur_p1<<<256, 512, 0, stream>>>(x, PScol, PSrow, Dg);
    schur_p2<<<32, 256, 0, stream>>>(PScol, PSrow, Dg, w, iso, Ab, Bb, S0, D0);
    schur_p3<<<2064, 256, 0, stream>>>(x, w, iso, Ab, Bb, S0, D0, out);
}

// Round 17
// 45.093 us; speedup vs baseline: 1.9683x; 1.0662x over previous
//
#include <hip/hip_runtime.h>
#include <math.h>

#define N 128
#define HID 512
#define NH (N * HID)                 // 65536
#define SNH ((size_t)N * NH)         // 8388608 elements per s
#define NPAIRS (N * (N + 1) / 2)     // 8256

typedef float vf4 __attribute__((ext_vector_type(4)));
union F4 { vf4 v; float f[4]; };
typedef unsigned int u32t;
typedef unsigned short u16t;

// bf16 pack/unpack (RNE)
__device__ __forceinline__ u32t pk2(float a, float b) {
    u32t ua = __float_as_uint(a), ub = __float_as_uint(b);
    ua = (ua + 0x7FFFu + ((ua >> 16) & 1u)) >> 16;
    ub = (ub + 0x7FFFu + ((ub >> 16) & 1u)) >> 16;
    return ua | (ub << 16);
}
__device__ __forceinline__ void stbf4(u16t* p, F4 t) {
    uint2 u; u.x = pk2(t.f[0], t.f[1]); u.y = pk2(t.f[2], t.f[3]);
    *reinterpret_cast<uint2*>(p) = u;
}
__device__ __forceinline__ F4 ldbf4(const u16t* p) {
    const uint2 u = *reinterpret_cast<const uint2*>(p);
    F4 r;
    r.f[0] = __uint_as_float(u.x << 16);
    r.f[1] = __uint_as_float(u.x & 0xFFFF0000u);
    r.f[2] = __uint_as_float(u.y << 16);
    r.f[3] = __uint_as_float(u.y & 0xFFFF0000u);
    return r;
}

// ---------------------------------------------------------------------------
// K1: stride-free dense-cube partial sums (R13 structure; bf16 PS stores).
// Block = (s, g=a-16-group, bq=b-quarter, hq=h-quarter): 2*8*4*4 = 256.
// ---------------------------------------------------------------------------
__global__ __launch_bounds__(512)
void schur_p1(const float* __restrict__ x, u16t* __restrict__ PScol,
              u16t* __restrict__ PSrow, float* __restrict__ Dg) {
    const int u  = blockIdx.x;            // 0..255
    const int hq = u & 3;
    const int bq = (u >> 2) & 3;
    const int g  = (u >> 4) & 7;
    const int s  = u >> 7;                // 0..1
    const int tid = threadIdx.x;
    const int f   = tid & 31;             // float4 within h-quarter
    const int bg  = tid >> 5;             // 0..15, 2 b's each
    const int b0  = bq * 32 + bg * 2;
    const int hoff = hq * 128 + f * 4;

    const float* xs   = x + (size_t)s * SNH;
    const float* base = xs + (size_t)(g * 16) * NH + b0 * HID + hoff;

    __shared__ F4 rowred[8][16][32];      // 64 KiB

    F4 acc0, acc1;
    acc0.v = (vf4)(0.f); acc1.v = (vf4)(0.f);

    #pragma unroll
    for (int c = 0; c < 2; ++c) {
        #pragma unroll
        for (int al = 0; al < 8; ++al) {
            const float* p = base + (size_t)(c * 8 + al) * NH;
            F4 v0; v0.v = *reinterpret_cast<const vf4*>(p);
            F4 v1; v1.v = *reinterpret_cast<const vf4*>(p + HID);
            acc0.v += v0.v;
            acc1.v += v1.v;
            F4 rs; rs.v = v0.v + v1.v;
            rowred[al][bg][f] = rs;
        }
        __syncthreads();
        if (tid < 256) {
            const int ar = tid >> 5;      // 0..7
            const int f2 = tid & 31;
            F4 t; t.v = (vf4)(0.f);
            #pragma unroll
            for (int k = 0; k < 16; ++k) t.v += rowred[ar][k][f2].v;
            const int a = g * 16 + c * 8 + ar;
            stbf4(PSrow + ((((size_t)s * 4 + bq) * N + a) * HID + hq * 128 + f2 * 4), t);
        }
        __syncthreads();
    }

    stbf4(PScol + ((((size_t)s * 8 + g) * N + b0) * HID + hoff), acc0);
    stbf4(PScol + ((((size_t)s * 8 + g) * N + b0 + 1) * HID + hoff), acc1);

    if (bq == (g >> 1)) {
        const int ar = tid >> 5;          // 0..15
        const int f2 = tid & 31;
        const int a  = g * 16 + ar;
        const vf4 dv = *reinterpret_cast<const vf4*>(
            xs + (size_t)a * NH + a * HID + hq * 128 + f2 * 4);
        *reinterpret_cast<vf4*>(Dg +
            (((size_t)s * N + a) * HID + hq * 128 + f2 * 4)) = dv;
    }
}

// ---------------------------------------------------------------------------
// K2: fold bf16 partials -> stats -> bf16 Xr/Yc + f32 Sv/Db.
// 32 blocks x 256 threads (R13 structure).
// ---------------------------------------------------------------------------
__global__ __launch_bounds__(256)
void schur_p2(const u16t* __restrict__ PScol, const u16t* __restrict__ PSrow,
              const float* __restrict__ Dg,
              u16t* __restrict__ Xr, u16t* __restrict__ Yc,
              float* __restrict__ Sv, float* __restrict__ Db) {
    const int bi = blockIdx.x;            // 0..31
    const int s  = bi >> 4;
    const int hc = bi & 15;               // 8 float4 per chunk
    const int tid = threadIdx.x;          // 0..255
    const int iq = tid >> 3;              // 0..31
    const int hf = tid & 7;
    const int h  = (hc * 8 + hf) * 4;     // float offset in [0,512)

    F4 sa[4], sb[4], dg[4];
    F4 T, D; T.v = (vf4)(0.f); D.v = (vf4)(0.f);
    #pragma unroll
    for (int k = 0; k < 4; ++k) {
        const int i = iq + 32 * k;
        F4 acc; acc.v = (vf4)(0.f);
        #pragma unroll
        for (int gg = 0; gg < 8; ++gg)
            acc.v += ldbf4(PScol + (((size_t)s * 8 + gg) * N + i) * HID + h).v;
        sa[k] = acc; T.v += acc.v;
        F4 accb; accb.v = (vf4)(0.f);
        #pragma unroll
        for (int qq = 0; qq < 4; ++qq)
            accb.v += ldbf4(PSrow + (((size_t)s * 4 + qq) * N + i) * HID + h).v;
        sb[k] = accb;
        dg[k].v = *reinterpret_cast<const vf4*>(Dg + ((size_t)s * N + i) * HID + h);
        D.v += dg[k].v;
    }

    __shared__ F4 redT[32][8];
    __shared__ F4 redD[32][8];
    __shared__ F4 shS[8];
    redT[iq][hf] = T;
    redD[iq][hf] = D;
    __syncthreads();
    if (iq == 0) {
        F4 Tt, Dd; Tt.v = (vf4)(0.f); Dd.v = (vf4)(0.f);
        #pragma unroll
        for (int q = 0; q < 32; ++q) { Tt.v += redT[q][hf].v; Dd.v += redD[q][hf].v; }
        F4 sh, db_;
        sh.v  = (Tt.v - Dd.v) * (1.0f / 16256.0f);   // /(n(n-1))
        db_.v = Dd.v * (1.0f / 128.0f);
        *reinterpret_cast<vf4*>(Sv + s * HID + h) = sh.v;
        *reinterpret_cast<vf4*>(Db + s * HID + h) = db_.v;
        shS[hf] = sh;
    }
    __syncthreads();

    const F4 sh = shS[hf];
    const float inv = 1.0f / 16128.0f;    // 1/(n(n-2))
    const size_t base = (size_t)s * N * HID;
    #pragma unroll
    for (int k = 0; k < 4; ++k) {
        const int i = iq + 32 * k;
        F4 r, c, xr, yc;
        r.v = sa[k].v - dg[k].v - 127.0f * sh.v;
        c.v = sb[k].v - dg[k].v - 127.0f * sh.v;
        xr.v = (127.0f * r.v + c.v) * inv;
        yc.v = (127.0f * c.v + r.v) * inv;
        stbf4(Xr + base + (size_t)i * HID + h, xr);
        stbf4(Yc + base + (size_t)i * HID + h, yc);
    }
}

// ---------------------------------------------------------------------------
// K3: output over triangular pairs (R13 math verbatim; bf16 Xr/Yc loads).
// 2064 blocks x 256 threads, XCD bijective swizzle, NT stores.
// ---------------------------------------------------------------------------
__global__ __launch_bounds__(256)
void schur_p3(const float* __restrict__ x, const float* __restrict__ w,
              const float* __restrict__ iso,
              const u16t* __restrict__ Xr, const u16t* __restrict__ Yc,
              const float* __restrict__ Sv, const float* __restrict__ Db,
              float* __restrict__ out) {
    const int t  = threadIdx.x;
    const int k  = t >> 7;                // pair slot 0/1
    const int ht = t & 127;
    const int hoff = ht * 4;

    float c[7];
    #pragma unroll
    for (int j = 0; j < 7; ++j) {
        float acc = 0.f;
        #pragma unroll
        for (int i = 0; i < 7; ++i) acc += w[i * 7 + j] * iso[i * 7 + j];
        c[j] = acc;
    }
    const float c1 = c[0], c2 = c[1], c3 = c[2], c4 = c[3], c5 = c[4];
    const float al = 0.5f * (c[5] + c[6]);
    const float be = 0.5f * (c[5] - c[6]);

    const int bid = blockIdx.x;
    const int swz = (bid & 7) * 258 + (bid >> 3);   // 2064 = 8*258, bijective
    const int pg0 = swz * 8;

    #define TRI_OFF(aa) ((aa) * N - (((aa) * ((aa) - 1)) >> 1))
    #pragma unroll
    for (int it = 0; it < 4; ++it) {
        const int pg = pg0 + it * 2 + k;      // global pair id, < 16512
        const int s  = (pg >= NPAIRS) ? 1 : 0;
        const int p  = pg - s * NPAIRS;

        int a = (int)((257.0f - sqrtf((float)(66049 - 8 * p))) * 0.5f);
        if (a < 0) a = 0;
        if (a > N - 1) a = N - 1;
        while (a > 0 && TRI_OFF(a) > p) --a;
        while (TRI_OFF(a + 1) <= p) ++a;
        const int b = a + (p - TRI_OFF(a));

        const size_t sbase    = (size_t)s * SNH;
        const size_t statbase = (size_t)s * N * HID;

        if (a == b) {
            F4 v;  v.v  = *reinterpret_cast<const vf4*>(x + sbase + ((size_t)a * N + a) * HID + hoff);
            F4 db; db.v = *reinterpret_cast<const vf4*>(Db + (size_t)s * HID + hoff);
            F4 o;
            #pragma unroll
            for (int j = 0; j < 4; ++j)
                o.f[j] = c1 * db.f[j] + c2 * (v.f[j] - db.f[j]);
            __builtin_nontemporal_store(o.v,
                reinterpret_cast<vf4*>(out + sbase + ((size_t)a * N + a) * HID + hoff));
            continue;
        }

        F4 va;  va.v  = *reinterpret_cast<const vf4*>(x + sbase + ((size_t)a * N + b) * HID + hoff);
        F4 vb;  vb.v  = *reinterpret_cast<const vf4*>(x + sbase + ((size_t)b * N + a) * HID + hoff);
        F4 xra = ldbf4(Xr + statbase + (size_t)a * HID + hoff);
        F4 xrb = ldbf4(Xr + statbase + (size_t)b * HID + hoff);
        F4 yca = ldbf4(Yc + statbase + (size_t)a * HID + hoff);
        F4 ycb = ldbf4(Yc + statbase + (size_t)b * HID + hoff);
        F4 sh;  sh.v  = *reinterpret_cast<const vf4*>(Sv + (size_t)s * HID + hoff);

        F4 oab, oba;
        #pragma unroll
        for (int j = 0; j < 4; ++j) {
            const float U = va.f[j] - sh.f[j] - xrb.f[j] - yca.f[j];
            const float V = vb.f[j] - sh.f[j] - xra.f[j] - ycb.f[j];
            oab.f[j] = c3 * sh.f[j] + c4 * xrb.f[j] + c5 * yca.f[j] + al * U + be * V;
            oba.f[j] = c3 * sh.f[j] + c4 * xra.f[j] + c5 * ycb.f[j] + al * V + be * U;
        }
        __builtin_nontemporal_store(oab.v,
            reinterpret_cast<vf4*>(out + sbase + ((size_t)a * N + b) * HID + hoff));
        __builtin_nontemporal_store(oba.v,
            reinterpret_cast<vf4*>(out + sbase + ((size_t)b * N + a) * HID + hoff));
    }
}

extern "C" void kernel_launch(void* const* d_in, const int* in_sizes, int n_in,
                              void* d_out, int out_size, void* d_ws, size_t ws_size,
                              hipStream_t stream) {
    const float* x   = (const float*)d_in[0];
    const float* w   = (const float*)d_in[1];
    const float* iso = (const float*)d_in[2];
    float* out = (float*)d_out;
    char* wsb  = (char*)d_ws;

    // byte-offset workspace layout (bf16 partials/stats)
    u16t*  PScol = (u16t*)(wsb);                         // 2 MB
    u16t*  PSrow = (u16t*)(wsb + (4u << 20));            // 1 MB
    float* Dg    = (float*)(wsb + (8u << 20));           // 512 KB
    u16t*  Xr    = (u16t*)(wsb + (12u << 20));           // 256 KB
    u16t*  Yc    = (u16t*)(wsb + (14u << 20));           // 256 KB
    float* Sv    = (float*)(wsb + (16u << 20));          // 4 KB
    float* Db    = (float*)(wsb + (16u << 20) + 65536);  // 4 KB

    schur_p1<<<256, 512, 0, stream>>>(x, PScol, PSrow, Dg);
    schur_p2<<<32, 256, 0, stream>>>(PScol, PSrow, Dg, Xr, Yc, Sv, Db);
    schur_p3<<<2064, 256, 0, stream>>>(x, w, iso, Xr, Yc, Sv, Db, out);
}